// Round 1
// baseline (407.219 us; speedup 1.0000x reference)
//
#include <hip/hip_runtime.h>
#include <hip/hip_bf16.h>
#include <stdint.h>

typedef __attribute__((ext_vector_type(4))) float f32x4;
typedef __attribute__((ext_vector_type(8))) short short8;

#define S_LEN 2048
#define BATCH 2
#define NH 16
#define NKV 4
#define DK 64

__device__ __forceinline__ ushort f2bf(float f) {
  union { float f; uint32_t u; } v; v.f = f;
  uint32_t u = v.u;
  u += 0x7fff + ((u >> 16) & 1);   // round-to-nearest-even
  return (ushort)(u >> 16);
}
__device__ __forceinline__ float bf2f(ushort h) {
  union { uint32_t u; float f; } v; v.u = ((uint32_t)h) << 16;
  return v.f;
}

// ---------------- f32 -> bf16 convert (vectorized) ----------------
__global__ void cvt_bf16_kernel(const float* __restrict__ in, ushort* __restrict__ out, int n4) {
  int i = blockIdx.x * blockDim.x + threadIdx.x;
  if (i >= n4) return;
  float4 v = ((const float4*)in)[i];
  ushort4 o;
  o.x = f2bf(v.x); o.y = f2bf(v.y); o.z = f2bf(v.z); o.w = f2bf(v.w);
  ((ushort4*)out)[i] = o;
}

// ---------------- RoPE cos/sin table: tab[0:65536)=cos, [65536:131072)=sin ----------------
__global__ void rope_table_kernel(float* __restrict__ tab) {
  int i = blockIdx.x * blockDim.x + threadIdx.x;   // 2048*32 threads
  int s = i >> 5, f = i & 31;
  float freq = (float)s * powf(10000.0f, -(float)f / 32.0f);
  tab[i] = cosf(freq);
  tab[65536 + i] = sinf(freq);
}

// ---------------- bf16 GEMM: C[M,N] = A[M,K] @ W[N,K]^T ----------------
// 128x128 tile, BK=32, 4 waves (each 64x64), mfma_f32_16x16x32_bf16.
template<int OUTF32>
__global__ __launch_bounds__(256) void gemm_bt(const ushort* __restrict__ A,
                                               const ushort* __restrict__ W,
                                               void* __restrict__ Cout,
                                               int M, int N, int K) {
  __shared__ ushort Al[128 * 32];
  __shared__ ushort Wl[128 * 32];
  const int t = threadIdx.x;
  const int lane = t & 63;
  const int w = t >> 6;
  const int wr = w >> 1, wc = w & 1;
  const int m0 = blockIdx.x * 128, n0 = blockIdx.y * 128;
  const int g = lane >> 4, q16 = lane & 15;

  f32x4 acc[4][4] = {};

  // staging: 512 chunks of 16B per 128x32 tile; each thread does 2 for A, 2 for W
  const int r0 = t >> 2, q0 = t & 3;
  const int r1 = r0 + 64;

  const int KSTEPS = K >> 5;
  for (int kt = 0; kt < KSTEPS; ++kt) {
    const int k0 = kt << 5;
    int4 a0 = *(const int4*)(A + (size_t)(m0 + r0) * K + k0 + q0 * 8);
    int4 a1 = *(const int4*)(A + (size_t)(m0 + r1) * K + k0 + q0 * 8);
    int4 w0 = *(const int4*)(W + (size_t)(n0 + r0) * K + k0 + q0 * 8);
    int4 w1 = *(const int4*)(W + (size_t)(n0 + r1) * K + k0 + q0 * 8);
    __syncthreads();
    *(int4*)&Al[r0 * 32 + q0 * 8] = a0;
    *(int4*)&Al[r1 * 32 + q0 * 8] = a1;
    *(int4*)&Wl[r0 * 32 + q0 * 8] = w0;
    *(int4*)&Wl[r1 * 32 + q0 * 8] = w1;
    __syncthreads();
    short8 af[4], wf[4];
    #pragma unroll
    for (int i = 0; i < 4; ++i)
      af[i] = *(const short8*)&Al[(wr * 64 + i * 16 + q16) * 32 + g * 8];
    #pragma unroll
    for (int j = 0; j < 4; ++j)
      wf[j] = *(const short8*)&Wl[(wc * 64 + j * 16 + q16) * 32 + g * 8];
    #pragma unroll
    for (int i = 0; i < 4; ++i)
      #pragma unroll
      for (int j = 0; j < 4; ++j)
        acc[i][j] = __builtin_amdgcn_mfma_f32_16x16x32_bf16(af[i], wf[j], acc[i][j], 0, 0, 0);
  }

  #pragma unroll
  for (int i = 0; i < 4; ++i)
    #pragma unroll
    for (int j = 0; j < 4; ++j) {
      int row0 = m0 + wr * 64 + i * 16 + g * 4;
      int col  = n0 + wc * 64 + j * 16 + q16;
      #pragma unroll
      for (int r = 0; r < 4; ++r) {
        if (OUTF32) ((float*)Cout)[(size_t)(row0 + r) * N + col] = acc[i][j][r];
        else        ((ushort*)Cout)[(size_t)(row0 + r) * N + col] = f2bf(acc[i][j][r]);
      }
    }
}

// ---------------- RoPE apply + head packing ----------------
// Qp [B*S][1024] -> Qh [B][16][S][64] (scaled by 1/8)
// Kp [B*S][256]  -> Kh [B][4][S][64]
// Vp [B*S][256]  -> Vt [B][4][64][S]   (transposed for PV B-fragments)
__global__ void rope_pack_kernel(const ushort* __restrict__ Qp, const ushort* __restrict__ Kp,
                                 const ushort* __restrict__ Vp, const float* __restrict__ tab,
                                 ushort* __restrict__ Qh, ushort* __restrict__ Kh,
                                 ushort* __restrict__ Vt) {
  int idx = blockIdx.x * blockDim.x + threadIdx.x;
  const int NQ = BATCH * S_LEN * NH * 32;    // 2097152
  const int NK = BATCH * S_LEN * NKV * 32;   // 524288
  const int NV = BATCH * S_LEN * NKV * 64;   // 1048576
  if (idx < NQ) {
    int d = idx & 31; int h = (idx >> 5) & 15; int s = (idx >> 9) & 2047; int b = idx >> 20;
    size_t src = (size_t)(b * 2048 + s) * 1024 + h * 64 + d;
    float q1 = bf2f(Qp[src]);
    float q2 = bf2f(Qp[src + 32]);
    float c = tab[s * 32 + d], sn = tab[65536 + s * 32 + d];
    float o1 = (q1 * c - q2 * sn) * 0.125f;   // fold 1/sqrt(D_K) into Q
    float o2 = (q2 * c + q1 * sn) * 0.125f;
    size_t base = ((size_t)(b * 16 + h) * 2048 + s) * 64 + d;
    Qh[base] = f2bf(o1); Qh[base + 32] = f2bf(o2);
  } else if (idx < NQ + NK) {
    int j = idx - NQ;
    int d = j & 31; int h = (j >> 5) & 3; int s = (j >> 7) & 2047; int b = j >> 18;
    size_t src = (size_t)(b * 2048 + s) * 256 + h * 64 + d;
    float q1 = bf2f(Kp[src]);
    float q2 = bf2f(Kp[src + 32]);
    float c = tab[s * 32 + d], sn = tab[65536 + s * 32 + d];
    float o1 = q1 * c - q2 * sn;
    float o2 = q2 * c + q1 * sn;
    size_t base = ((size_t)(b * 4 + h) * 2048 + s) * 64 + d;
    Kh[base] = f2bf(o1); Kh[base + 32] = f2bf(o2);
  } else if (idx < NQ + NK + NV) {
    int j = idx - NQ - NK;
    int s = j & 2047; int d = (j >> 11) & 63; int h = (j >> 17) & 3; int b = j >> 19;
    Vt[((size_t)(b * 4 + h) * 64 + d) * 2048 + s] =
        Vp[(size_t)(b * 2048 + s) * 256 + h * 64 + d];
  }
}

// ---------------- causal GQA flash attention ----------------
// grid.x = S/64 q-tiles, grid.y = B*NH. 4 waves/block, 16 q-rows/wave, KV block 64.
// K/V fragments read directly from global (L2-resident per kv-head).
__global__ __launch_bounds__(256) void fattn_kernel(const ushort* __restrict__ Qh,
                                                    const ushort* __restrict__ Kh,
                                                    const ushort* __restrict__ Vt,
                                                    ushort* __restrict__ AO) {
  __shared__ ushort Plds[4][16][72];  // per-wave P tile, padded (+8) vs bank conflicts
  const int t = threadIdx.x, lane = t & 63, wv = t >> 6;
  const int g = lane >> 4, q16 = lane & 15;
  const int hh = blockIdx.y;                 // b*16 + h
  const int b = hh >> 4, h = hh & 15;
  const int kvh = h >> 2;
  const int q0 = blockIdx.x * 64 + wv * 16;

  const ushort* Qbase = Qh + ((size_t)hh * 2048 + q0) * 64;
  const ushort* Kbase = Kh + (size_t)(b * 4 + kvh) * 2048 * 64;
  const ushort* Vbase = Vt + (size_t)(b * 4 + kvh) * 64 * 2048;

  short8 aq[2];
  aq[0] = *(const short8*)(Qbase + (size_t)q16 * 64 + g * 8);
  aq[1] = *(const short8*)(Qbase + (size_t)q16 * 64 + 32 + g * 8);

  f32x4 acc[4] = {};
  float mrun[4] = {-1e30f, -1e30f, -1e30f, -1e30f};
  float lrun[4] = {0.f, 0.f, 0.f, 0.f};

  const int nkb = blockIdx.x + 1;   // causal: only kv blocks up to the q tile
  for (int kb = 0; kb < nkb; ++kb) {
    const int k0 = kb * 64;
    f32x4 sA[4] = {};
    #pragma unroll
    for (int kk = 0; kk < 2; ++kk)
      #pragma unroll
      for (int nt = 0; nt < 4; ++nt) {
        short8 bk = *(const short8*)(Kbase + (size_t)(k0 + nt * 16 + q16) * 64 + kk * 32 + g * 8);
        sA[nt] = __builtin_amdgcn_mfma_f32_16x16x32_bf16(aq[kk], bk, sA[nt], 0, 0, 0);
      }
    if (kb == nkb - 1) {   // causal mask on the diagonal block
      #pragma unroll
      for (int nt = 0; nt < 4; ++nt)
        #pragma unroll
        for (int r = 0; r < 4; ++r) {
          int col = k0 + nt * 16 + q16, row = q0 + g * 4 + r;
          if (col > row) sA[nt][r] = -1e30f;
        }
    }
    float ps[4][4];
    float al[4];
    #pragma unroll
    for (int r = 0; r < 4; ++r) {
      float v = fmaxf(fmaxf(sA[0][r], sA[1][r]), fmaxf(sA[2][r], sA[3][r]));
      #pragma unroll
      for (int moff = 1; moff < 16; moff <<= 1) v = fmaxf(v, __shfl_xor(v, moff));
      float nm = fmaxf(mrun[r], v);
      al[r] = __expf(mrun[r] - nm);
      mrun[r] = nm;
    }
    #pragma unroll
    for (int r = 0; r < 4; ++r) {
      float rs = 0.f;
      #pragma unroll
      for (int nt = 0; nt < 4; ++nt) {
        float p = __expf(sA[nt][r] - mrun[r]);
        ps[nt][r] = p; rs += p;
      }
      #pragma unroll
      for (int moff = 1; moff < 16; moff <<= 1) rs += __shfl_xor(rs, moff);
      lrun[r] = lrun[r] * al[r] + rs;
    }
    #pragma unroll
    for (int dt = 0; dt < 4; ++dt)
      #pragma unroll
      for (int r = 0; r < 4; ++r) acc[dt][r] *= al[r];
    // P (C-layout) -> LDS -> A-layout fragments
    #pragma unroll
    for (int nt = 0; nt < 4; ++nt)
      #pragma unroll
      for (int r = 0; r < 4; ++r)
        Plds[wv][g * 4 + r][nt * 16 + q16] = f2bf(ps[nt][r]);
    #pragma unroll
    for (int kk2 = 0; kk2 < 2; ++kk2) {
      short8 pa = *(const short8*)&Plds[wv][q16][kk2 * 32 + g * 8];
      #pragma unroll
      for (int dt = 0; dt < 4; ++dt) {
        short8 bv = *(const short8*)(Vbase + (size_t)(dt * 16 + q16) * 2048 + k0 + kk2 * 32 + g * 8);
        acc[dt] = __builtin_amdgcn_mfma_f32_16x16x32_bf16(pa, bv, acc[dt], 0, 0, 0);
      }
    }
  }
  #pragma unroll
  for (int dt = 0; dt < 4; ++dt)
    #pragma unroll
    for (int r = 0; r < 4; ++r) {
      float o = acc[dt][r] / lrun[r];
      AO[((size_t)(b * 2048) + q0 + g * 4 + r) * 1024 + h * 64 + dt * 16 + q16] = f2bf(o);
    }
}

// ---------------- launch ----------------
extern "C" void kernel_launch(void* const* d_in, const int* in_sizes, int n_in,
                              void* d_out, int out_size, void* d_ws, size_t ws_size,
                              hipStream_t stream) {
  const float* query = (const float*)d_in[0];
  const float* key   = (const float*)d_in[1];
  const float* value = (const float*)d_in[2];
  const float* Wq    = (const float*)d_in[3];
  const float* Wk    = (const float*)d_in[4];
  const float* Wv    = (const float*)d_in[5];
  const float* Wo    = (const float*)d_in[6];
  float* out = (float*)d_out;

  char* ws = (char*)d_ws;
  size_t off = 0;
  auto alloc = [&](size_t bytes) {
    void* p = ws + off; off += (bytes + 255) & ~255ULL; return p;
  };
  ushort* qbf = (ushort*)alloc(4096ULL * 1024 * 2);
  ushort* kbf = (ushort*)alloc(4096ULL * 1024 * 2);
  ushort* vbf = (ushort*)alloc(4096ULL * 1024 * 2);
  ushort* wqb = (ushort*)alloc(1024ULL * 1024 * 2);
  ushort* wkb = (ushort*)alloc(256ULL * 1024 * 2);
  ushort* wvb = (ushort*)alloc(256ULL * 1024 * 2);
  ushort* wob = (ushort*)alloc(1024ULL * 1024 * 2);
  ushort* Qp  = (ushort*)alloc(4096ULL * 1024 * 2);
  ushort* Kp  = (ushort*)alloc(4096ULL * 256 * 2);
  ushort* Vp  = (ushort*)alloc(4096ULL * 256 * 2);
  ushort* Qh  = (ushort*)alloc(4096ULL * 1024 * 2);
  ushort* Kh  = (ushort*)alloc(4096ULL * 256 * 2);
  ushort* Vt  = (ushort*)alloc(4096ULL * 256 * 2);
  ushort* AO  = (ushort*)alloc(4096ULL * 1024 * 2);
  float*  tab = (float*)alloc(2048ULL * 32 * 4 * 2);

  auto cvt = [&](const float* in, ushort* o, size_t n) {
    int n4 = (int)(n / 4);
    cvt_bf16_kernel<<<(n4 + 255) / 256, 256, 0, stream>>>(in, o, n4);
  };
  cvt(query, qbf, 4096ULL * 1024);
  cvt(key,   kbf, 4096ULL * 1024);
  cvt(value, vbf, 4096ULL * 1024);
  cvt(Wq, wqb, 1024ULL * 1024);
  cvt(Wk, wkb, 256ULL * 1024);
  cvt(Wv, wvb, 256ULL * 1024);
  cvt(Wo, wob, 1024ULL * 1024);
  rope_table_kernel<<<256, 256, 0, stream>>>((float*)tab);

  gemm_bt<0><<<dim3(32, 8), 256, 0, stream>>>(qbf, wqb, Qp, 4096, 1024, 1024);
  gemm_bt<0><<<dim3(32, 2), 256, 0, stream>>>(kbf, wkb, Kp, 4096, 256, 1024);
  gemm_bt<0><<<dim3(32, 2), 256, 0, stream>>>(vbf, wvb, Vp, 4096, 256, 1024);

  rope_pack_kernel<<<(3670016) / 256, 256, 0, stream>>>(Qp, Kp, Vp, tab, Qh, Kh, Vt);

  fattn_kernel<<<dim3(32, 32), 256, 0, stream>>>(Qh, Kh, Vt, AO);

  gemm_bt<1><<<dim3(32, 8), 256, 0, stream>>>(AO, wob, out, 4096, 1024, 1024);
}

// Round 2
// 255.266 us; speedup vs baseline: 1.5953x; 1.5953x over previous
//
#include <hip/hip_runtime.h>
#include <hip/hip_bf16.h>
#include <stdint.h>

typedef __attribute__((ext_vector_type(4))) float f32x4;
typedef __attribute__((ext_vector_type(8))) short short8;

#define S_LEN 2048
#define BATCH 2
#define NH 16
#define NKV 4
#define DK 64

__device__ __forceinline__ ushort f2bf(float f) {
  union { float f; uint32_t u; } v; v.f = f;
  uint32_t u = v.u;
  u += 0x7fff + ((u >> 16) & 1);   // round-to-nearest-even
  return (ushort)(u >> 16);
}
__device__ __forceinline__ float bf2f(ushort h) {
  union { uint32_t u; float f; } v; v.u = ((uint32_t)h) << 16;
  return v.f;
}

// async global->LDS, 16B per lane; LDS dest = wave-uniform base + lane*16
__device__ __forceinline__ void gld16(const ushort* g, ushort* l) {
  __builtin_amdgcn_global_load_lds((const __attribute__((address_space(1))) void*)g,
                                   (__attribute__((address_space(3))) void*)l,
                                   16, 0, 0);
}

// DPP-based reductions across each 16-lane row (VALU pipe, no LDS traffic)
template<int CTRL>
__device__ __forceinline__ float dpp_movf(float x) {
  return __int_as_float(__builtin_amdgcn_update_dpp(0, __float_as_int(x), CTRL, 0xF, 0xF, true));
}
__device__ __forceinline__ float rowred_max16(float v) {
  v = fmaxf(v, dpp_movf<0xB1>(v));    // quad_perm xor1
  v = fmaxf(v, dpp_movf<0x4E>(v));    // quad_perm xor2
  v = fmaxf(v, dpp_movf<0x141>(v));   // row_half_mirror
  v = fmaxf(v, dpp_movf<0x140>(v));   // row_mirror
  return v;
}
__device__ __forceinline__ float rowred_sum16(float v) {
  v += dpp_movf<0xB1>(v);
  v += dpp_movf<0x4E>(v);
  v += dpp_movf<0x141>(v);
  v += dpp_movf<0x140>(v);
  return v;
}

// ---------------- f32 -> bf16 convert (vectorized) ----------------
__global__ void cvt_bf16_kernel(const float* __restrict__ in, ushort* __restrict__ out, int n4) {
  int i = blockIdx.x * blockDim.x + threadIdx.x;
  if (i >= n4) return;
  float4 v = ((const float4*)in)[i];
  ushort4 o;
  o.x = f2bf(v.x); o.y = f2bf(v.y); o.z = f2bf(v.z); o.w = f2bf(v.w);
  ((ushort4*)out)[i] = o;
}

// ---------------- RoPE cos/sin table ----------------
__global__ void rope_table_kernel(float* __restrict__ tab) {
  int i = blockIdx.x * blockDim.x + threadIdx.x;   // 2048*32 threads
  int s = i >> 5, f = i & 31;
  float freq = (float)s * powf(10000.0f, -(float)f / 32.0f);
  tab[i] = cosf(freq);
  tab[65536 + i] = sinf(freq);
}

// ---------------- bf16 GEMM: C[M,N] = A[M,K] @ W[N,K]^T ----------------
// 128x128 tile, BK=32, 4 waves (each 64x64), global_load_lds staging.
template<int OUTF32>
__global__ __launch_bounds__(256) void gemm_bt(const ushort* __restrict__ A,
                                               const ushort* __restrict__ W,
                                               void* __restrict__ Cout,
                                               int M, int N, int K) {
  __shared__ ushort Al[128 * 32];
  __shared__ ushort Wl[128 * 32];
  const int t = threadIdx.x;
  const int lane = t & 63;
  const int w = t >> 6;
  const int wr = w >> 1, wc = w & 1;
  const int m0 = blockIdx.x * 128, n0 = blockIdx.y * 128;
  const int g = lane >> 4, q16 = lane & 15;

  f32x4 acc[4][4] = {};

  // staging: wave w owns rows [w*32, w*32+32) of both tiles; 16 rows / 1KB per call
  const int lrow = lane >> 2, lcol = (lane & 3) * 8;
  const ushort* Ap = A + (size_t)(m0 + w * 32 + lrow) * K + lcol;
  const ushort* Wp = W + (size_t)(n0 + w * 32 + lrow) * K + lcol;
  ushort* Ab0 = &Al[(w * 32) * 32];
  ushort* Ab1 = &Al[(w * 32 + 16) * 32];
  ushort* Wb0 = &Wl[(w * 32) * 32];
  ushort* Wb1 = &Wl[(w * 32 + 16) * 32];

  const int KSTEPS = K >> 5;
  for (int kt = 0; kt < KSTEPS; ++kt) {
    const int k0 = kt << 5;
    __syncthreads();   // prior iteration's ds_reads done before overwrite
    gld16(Ap + k0, Ab0);
    gld16(Ap + (size_t)16 * K + k0, Ab1);
    gld16(Wp + k0, Wb0);
    gld16(Wp + (size_t)16 * K + k0, Wb1);
    __syncthreads();   // drains vmcnt -> LDS tiles ready
    short8 af[4], wf[4];
    #pragma unroll
    for (int i = 0; i < 4; ++i)
      af[i] = *(const short8*)&Al[(wr * 64 + i * 16 + q16) * 32 + g * 8];
    #pragma unroll
    for (int j = 0; j < 4; ++j)
      wf[j] = *(const short8*)&Wl[(wc * 64 + j * 16 + q16) * 32 + g * 8];
    #pragma unroll
    for (int i = 0; i < 4; ++i)
      #pragma unroll
      for (int j = 0; j < 4; ++j)
        acc[i][j] = __builtin_amdgcn_mfma_f32_16x16x32_bf16(af[i], wf[j], acc[i][j], 0, 0, 0);
  }

  #pragma unroll
  for (int i = 0; i < 4; ++i)
    #pragma unroll
    for (int j = 0; j < 4; ++j) {
      int row0 = m0 + wr * 64 + i * 16 + g * 4;
      int col  = n0 + wc * 64 + j * 16 + q16;
      #pragma unroll
      for (int r = 0; r < 4; ++r) {
        if (OUTF32) ((float*)Cout)[(size_t)(row0 + r) * N + col] = acc[i][j][r];
        else        ((ushort*)Cout)[(size_t)(row0 + r) * N + col] = f2bf(acc[i][j][r]);
      }
    }
}

// ---------------- RoPE apply + head packing ----------------
__global__ void rope_pack_kernel(const ushort* __restrict__ Qp, const ushort* __restrict__ Kp,
                                 const ushort* __restrict__ Vp, const float* __restrict__ tab,
                                 ushort* __restrict__ Qh, ushort* __restrict__ Kh,
                                 ushort* __restrict__ Vt) {
  int idx = blockIdx.x * blockDim.x + threadIdx.x;
  const int NQ = BATCH * S_LEN * NH * 32;    // 2097152
  const int NK = BATCH * S_LEN * NKV * 32;   // 524288
  const int NV = BATCH * S_LEN * NKV * 64;   // 1048576
  if (idx < NQ) {
    int d = idx & 31; int h = (idx >> 5) & 15; int s = (idx >> 9) & 2047; int b = idx >> 20;
    size_t src = (size_t)(b * 2048 + s) * 1024 + h * 64 + d;
    float q1 = bf2f(Qp[src]);
    float q2 = bf2f(Qp[src + 32]);
    float c = tab[s * 32 + d], sn = tab[65536 + s * 32 + d];
    float o1 = (q1 * c - q2 * sn) * 0.125f;   // fold 1/sqrt(D_K) into Q
    float o2 = (q2 * c + q1 * sn) * 0.125f;
    size_t base = ((size_t)(b * 16 + h) * 2048 + s) * 64 + d;
    Qh[base] = f2bf(o1); Qh[base + 32] = f2bf(o2);
  } else if (idx < NQ + NK) {
    int j = idx - NQ;
    int d = j & 31; int h = (j >> 5) & 3; int s = (j >> 7) & 2047; int b = j >> 18;
    size_t src = (size_t)(b * 2048 + s) * 256 + h * 64 + d;
    float q1 = bf2f(Kp[src]);
    float q2 = bf2f(Kp[src + 32]);
    float c = tab[s * 32 + d], sn = tab[65536 + s * 32 + d];
    float o1 = q1 * c - q2 * sn;
    float o2 = q2 * c + q1 * sn;
    size_t base = ((size_t)(b * 4 + h) * 2048 + s) * 64 + d;
    Kh[base] = f2bf(o1); Kh[base + 32] = f2bf(o2);
  } else if (idx < NQ + NK + NV) {
    int j = idx - NQ - NK;
    int s = j & 2047; int d = (j >> 11) & 63; int h = (j >> 17) & 3; int b = j >> 19;
    Vt[((size_t)(b * 4 + h) * 64 + d) * 2048 + s] =
        Vp[(size_t)(b * 2048 + s) * 256 + h * 64 + d];
  }
}

// ---------------- causal GQA flash attention ----------------
// grid (16, 32): block handles q-tile PAIR {x, 31-x} -> uniform 33 kv-iterations.
// 4 waves/block, 16 q-rows/wave per tile, KV block 64, K/V direct from global
// with register prefetch; DPP softmax reductions.
__global__ __launch_bounds__(256) void fattn_kernel(const ushort* __restrict__ Qh,
                                                    const ushort* __restrict__ Kh,
                                                    const ushort* __restrict__ Vt,
                                                    ushort* __restrict__ AO) {
  __shared__ ushort Plds[4][16][72];
  const int t = threadIdx.x, lane = t & 63, wv = t >> 6;
  const int g = lane >> 4, q16 = lane & 15;
  const int hh = blockIdx.y;                 // b*16 + h
  const int b = hh >> 4, h = hh & 15;
  const int kvh = h >> 2;
  const ushort* Kbase = Kh + (size_t)(b * 4 + kvh) * 2048 * 64;
  const ushort* Vbase = Vt + (size_t)(b * 4 + kvh) * 64 * 2048;

  for (int pass = 0; pass < 2; ++pass) {
    const int qt = pass ? (31 - (int)blockIdx.x) : (int)blockIdx.x;
    const int q0 = qt * 64 + wv * 16;
    const ushort* Qbase = Qh + ((size_t)hh * 2048 + q0) * 64;

    short8 aq[2];
    aq[0] = *(const short8*)(Qbase + (size_t)q16 * 64 + g * 8);
    aq[1] = *(const short8*)(Qbase + (size_t)q16 * 64 + 32 + g * 8);

    f32x4 acc[4] = {};
    float mrun[4], lrun[4];
    #pragma unroll
    for (int r = 0; r < 4; ++r) { mrun[r] = -1e30f; lrun[r] = 0.f; }

    const int nkb = qt + 1;
    // preload K fragments for kb=0
    short8 bk[8];
    #pragma unroll
    for (int kk = 0; kk < 2; ++kk)
      #pragma unroll
      for (int nt = 0; nt < 4; ++nt)
        bk[kk * 4 + nt] = *(const short8*)(Kbase + (size_t)(nt * 16 + q16) * 64 + kk * 32 + g * 8);

    for (int kb = 0; kb < nkb; ++kb) {
      const int k0 = kb * 64;
      // V fragments: independent of softmax, issue early
      short8 bv[8];
      #pragma unroll
      for (int kk2 = 0; kk2 < 2; ++kk2)
        #pragma unroll
        for (int dt = 0; dt < 4; ++dt)
          bv[kk2 * 4 + dt] = *(const short8*)(Vbase + (size_t)(dt * 16 + q16) * 2048 + k0 + kk2 * 32 + g * 8);

      f32x4 sA[4] = {};
      #pragma unroll
      for (int kk = 0; kk < 2; ++kk)
        #pragma unroll
        for (int nt = 0; nt < 4; ++nt)
          sA[nt] = __builtin_amdgcn_mfma_f32_16x16x32_bf16(aq[kk], bk[kk * 4 + nt], sA[nt], 0, 0, 0);

      // prefetch next K tile while softmax runs
      short8 bk2[8];
      const bool more = (kb + 1 < nkb);
      if (more) {
        #pragma unroll
        for (int kk = 0; kk < 2; ++kk)
          #pragma unroll
          for (int nt = 0; nt < 4; ++nt)
            bk2[kk * 4 + nt] = *(const short8*)(Kbase + (size_t)(k0 + 64 + nt * 16 + q16) * 64 + kk * 32 + g * 8);
      }

      if (kb == nkb - 1) {   // causal mask on the diagonal block
        #pragma unroll
        for (int nt = 0; nt < 4; ++nt)
          #pragma unroll
          for (int r = 0; r < 4; ++r) {
            int col = k0 + nt * 16 + q16, row = q0 + g * 4 + r;
            if (col > row) sA[nt][r] = -1e30f;
          }
      }

      float ps[4][4];
      float al[4];
      #pragma unroll
      for (int r = 0; r < 4; ++r) {
        float v = fmaxf(fmaxf(sA[0][r], sA[1][r]), fmaxf(sA[2][r], sA[3][r]));
        v = rowred_max16(v);
        float nm = fmaxf(mrun[r], v);
        al[r] = __expf(mrun[r] - nm);
        mrun[r] = nm;
        float rs = 0.f;
        #pragma unroll
        for (int nt = 0; nt < 4; ++nt) {
          float p = __expf(sA[nt][r] - nm);
          ps[nt][r] = p; rs += p;
        }
        rs = rowred_sum16(rs);
        lrun[r] = lrun[r] * al[r] + rs;
      }
      #pragma unroll
      for (int dt = 0; dt < 4; ++dt)
        #pragma unroll
        for (int r = 0; r < 4; ++r) acc[dt][r] *= al[r];

      // P (C-layout) -> LDS -> A-layout fragments
      #pragma unroll
      for (int nt = 0; nt < 4; ++nt)
        #pragma unroll
        for (int r = 0; r < 4; ++r)
          Plds[wv][g * 4 + r][nt * 16 + q16] = f2bf(ps[nt][r]);
      #pragma unroll
      for (int kk2 = 0; kk2 < 2; ++kk2) {
        short8 pa = *(const short8*)&Plds[wv][q16][kk2 * 32 + g * 8];
        #pragma unroll
        for (int dt = 0; dt < 4; ++dt)
          acc[dt] = __builtin_amdgcn_mfma_f32_16x16x32_bf16(pa, bv[kk2 * 4 + dt], acc[dt], 0, 0, 0);
      }

      if (more) {
        #pragma unroll
        for (int i = 0; i < 8; ++i) bk[i] = bk2[i];
      }
    }

    #pragma unroll
    for (int r = 0; r < 4; ++r) lrun[r] = 1.0f / lrun[r];
    #pragma unroll
    for (int dt = 0; dt < 4; ++dt)
      #pragma unroll
      for (int r = 0; r < 4; ++r) {
        float o = acc[dt][r] * lrun[r];
        AO[((size_t)(b * 2048) + q0 + g * 4 + r) * 1024 + h * 64 + dt * 16 + q16] = f2bf(o);
      }
  }
}

// ---------------- launch ----------------
extern "C" void kernel_launch(void* const* d_in, const int* in_sizes, int n_in,
                              void* d_out, int out_size, void* d_ws, size_t ws_size,
                              hipStream_t stream) {
  const float* query = (const float*)d_in[0];
  const float* key   = (const float*)d_in[1];
  const float* value = (const float*)d_in[2];
  const float* Wq    = (const float*)d_in[3];
  const float* Wk    = (const float*)d_in[4];
  const float* Wv    = (const float*)d_in[5];
  const float* Wo    = (const float*)d_in[6];
  float* out = (float*)d_out;

  char* ws = (char*)d_ws;
  size_t off = 0;
  auto alloc = [&](size_t bytes) {
    void* p = ws + off; off += (bytes + 255) & ~255ULL; return p;
  };
  ushort* qbf = (ushort*)alloc(4096ULL * 1024 * 2);
  ushort* kbf = (ushort*)alloc(4096ULL * 1024 * 2);
  ushort* vbf = (ushort*)alloc(4096ULL * 1024 * 2);
  ushort* wqb = (ushort*)alloc(1024ULL * 1024 * 2);
  ushort* wkb = (ushort*)alloc(256ULL * 1024 * 2);
  ushort* wvb = (ushort*)alloc(256ULL * 1024 * 2);
  ushort* wob = (ushort*)alloc(1024ULL * 1024 * 2);
  ushort* Qp  = (ushort*)alloc(4096ULL * 1024 * 2);
  ushort* Kp  = (ushort*)alloc(4096ULL * 256 * 2);
  ushort* Vp  = (ushort*)alloc(4096ULL * 256 * 2);
  ushort* Qh  = (ushort*)alloc(4096ULL * 1024 * 2);
  ushort* Kh  = (ushort*)alloc(4096ULL * 256 * 2);
  ushort* Vt  = (ushort*)alloc(4096ULL * 256 * 2);
  ushort* AO  = (ushort*)alloc(4096ULL * 1024 * 2);
  float*  tab = (float*)alloc(2048ULL * 32 * 4 * 2);

  auto cvt = [&](const float* in, ushort* o, size_t n) {
    int n4 = (int)(n / 4);
    cvt_bf16_kernel<<<(n4 + 255) / 256, 256, 0, stream>>>(in, o, n4);
  };
  cvt(query, qbf, 4096ULL * 1024);
  cvt(key,   kbf, 4096ULL * 1024);
  cvt(value, vbf, 4096ULL * 1024);
  cvt(Wq, wqb, 1024ULL * 1024);
  cvt(Wk, wkb, 256ULL * 1024);
  cvt(Wv, wvb, 256ULL * 1024);
  cvt(Wo, wob, 1024ULL * 1024);
  rope_table_kernel<<<256, 256, 0, stream>>>((float*)tab);

  gemm_bt<0><<<dim3(32, 8), 256, 0, stream>>>(qbf, wqb, Qp, 4096, 1024, 1024);
  gemm_bt<0><<<dim3(32, 2), 256, 0, stream>>>(kbf, wkb, Kp, 4096, 256, 1024);
  gemm_bt<0><<<dim3(32, 2), 256, 0, stream>>>(vbf, wvb, Vp, 4096, 256, 1024);

  rope_pack_kernel<<<(3670016) / 256, 256, 0, stream>>>(Qp, Kp, Vp, tab, Qh, Kh, Vt);

  fattn_kernel<<<dim3(16, 32), 256, 0, stream>>>(Qh, Kh, Vt, AO);

  gemm_bt<1><<<dim3(32, 8), 256, 0, stream>>>(AO, wob, out, 4096, 1024, 1024);
}